// Round 3
// baseline (630.984 us; speedup 1.0000x reference)
//
#include <hip/hip_runtime.h>

#define BB 16
#define CC 64
#define NN 65536
#define NBV 4

// ws layout (fp32 elements):
//   score  : B*N
//   bval   : B*64
//   bidx   : B*64 (int)
//   wpart  : B*64*64
//   sspart : B*64
// total ~4.47 MB

__global__ void k_init(const float* __restrict__ sc_in,
                       float* __restrict__ score,
                       float* __restrict__ sel_out) {
    int i = blockIdx.x * 256 + threadIdx.x;   // covers B*N exactly
    score[i] = sc_in[i];
    sel_out[i] = 0.f;   // selectedPos = zeros
}

// Per-batch argmax partials: 64 blocks/batch, each over 1024 contiguous scores.
// Tie rule: larger value wins; equal value -> smaller index (np.argmax = first max).
__global__ void k_argmax1(const float* __restrict__ score,
                          float* __restrict__ bval, int* __restrict__ bidx) {
    int b = blockIdx.y, blk = blockIdx.x, tid = threadIdx.x;
    const float* s = score + (size_t)b * NN + blk * 1024;
    float v = -1e30f; int vi = 0x7fffffff;
    #pragma unroll
    for (int k = 0; k < 4; k++) {
        int idx = k * 256 + tid;              // ascending per thread
        float xv = s[idx];
        if (xv > v) { v = xv; vi = blk * 1024 + idx; }  // strict > keeps earliest
    }
    __shared__ float sv[256]; __shared__ int si[256];
    sv[tid] = v; si[tid] = vi;
    __syncthreads();
    for (int st = 128; st > 0; st >>= 1) {
        if (tid < st) {
            float ov = sv[tid + st]; int oi = si[tid + st];
            if (ov > sv[tid] || (ov == sv[tid] && oi < si[tid])) { sv[tid] = ov; si[tid] = oi; }
        }
        __syncthreads();
    }
    if (tid == 0) { bval[b * 64 + blk] = sv[0]; bidx[b * 64 + blk] = si[0]; }
}

// Main per-iteration kernel. grid = (64, B), 256 threads.
// Fuses argmax stage-2 (redundant per block, cheap) + raw-vector fetch; then
// per thread: 4 pixels, 64 fp32 channels in VGPRs, d2 -> sim -> weighted acc.
// Per-block partial sums, no atomics.
__global__ __launch_bounds__(256, 2)
void k_iter(const float* __restrict__ x, float* __restrict__ score,
            const float* __restrict__ bval, const int* __restrict__ bidx,
            float* __restrict__ wpart, float* __restrict__ sspart,
            float* __restrict__ sim_out, int iter) {
    int b = blockIdx.y, blk = blockIdx.x, tid = threadIdx.x;
    int lane = tid & 63, wv = tid >> 6;
    __shared__ float raw_s[64];
    __shared__ float lw[4][64];
    __shared__ float ls[4];

    if (tid < 64) {   // wave 0: finish argmax, fetch selected pixel's features
        float v = bval[b * 64 + tid]; int vi = bidx[b * 64 + tid];
        #pragma unroll
        for (int off = 32; off >= 1; off >>= 1) {
            float ov = __shfl_down(v, off, 64); int oi = __shfl_down(vi, off, 64);
            if (ov > v || (ov == v && oi < vi)) { v = ov; vi = oi; }
        }
        int ind = __shfl(vi, 0, 64);
        raw_s[tid] = x[((size_t)b * 64 + tid) * NN + ind];
    }
    __syncthreads();

    float acc[64];
    #pragma unroll
    for (int c = 0; c < 64; c++) acc[c] = 0.f;
    float ssacc = 0.f;

    const float* xb = x + (size_t)b * 64 * NN;
    #pragma unroll 1
    for (int p = 0; p < 4; p++) {
        int n = blk * 1024 + p * 256 + tid;
        float xv[64];
        #pragma unroll
        for (int c = 0; c < 64; c++) xv[c] = xb[(size_t)c * NN + n];
        float d2 = 0.f;
        #pragma unroll
        for (int c = 0; c < 64; c++) { float df = xv[c] - raw_s[c]; d2 = fmaf(df, df, d2); }
        float sim = expf(-sqrtf(fmaxf(d2, 1e-12f)) * (1.0f / 20.0f));
        sim_out[((size_t)(b * 4 + iter)) * NN + n] = sim;
        if (iter < 3) score[(size_t)b * NN + n] *= (1.0f - sim);
        ssacc += sim;
        #pragma unroll
        for (int c = 0; c < 64; c++) acc[c] = fmaf(sim, xv[c], acc[c]);
    }

    // per-wave reduce each channel, stash wave partials in LDS
    #pragma unroll
    for (int c = 0; c < 64; c++) {
        float v = acc[c];
        #pragma unroll
        for (int off = 32; off >= 1; off >>= 1) v += __shfl_down(v, off, 64);
        if (lane == 0) lw[wv][c] = v;
    }
    {
        float v = ssacc;
        #pragma unroll
        for (int off = 32; off >= 1; off >>= 1) v += __shfl_down(v, off, 64);
        if (lane == 0) ls[wv] = v;
    }
    __syncthreads();
    if (tid < 64)
        wpart[(((size_t)b * 64) + blk) * 64 + tid] = lw[0][tid] + lw[1][tid] + lw[2][tid] + lw[3][tid];
    if (tid == 64)
        sspart[b * 64 + blk] = ls[0] + ls[1] + ls[2] + ls[3];
}

__global__ void k_fin(const float* __restrict__ wpart, const float* __restrict__ sspart,
                      float* __restrict__ vec_out, int iter) {
    int b = blockIdx.x, tid = threadIdx.x;  // 64 threads
    float w = 0.f;
    for (int blk = 0; blk < 64; blk++) w += wpart[(((size_t)b * 64) + blk) * 64 + tid];
    float ss = 0.f;
    for (int blk = 0; blk < 64; blk++) ss += sspart[b * 64 + blk];
    vec_out[(b * 4 + iter) * 64 + tid] = w / ss;
}

extern "C" void kernel_launch(void* const* d_in, const int* in_sizes, int n_in,
                              void* d_out, int out_size, void* d_ws, size_t ws_size,
                              hipStream_t stream) {
    const float* x = (const float*)d_in[0];          // [B,C,H,W] fp32
    const float* sc_in = (const float*)d_in[1];      // [B,N] fp32
    float* out = (float*)d_out;                      // fp32 outputs
    float* vec_out = out;                            // B*4*C
    float* sim_out = vec_out + (size_t)BB * 4 * CC;  // B*4*N
    float* sel_out = sim_out + (size_t)BB * 4 * NN;  // B*N

    float* ws = (float*)d_ws;
    float* score = ws;                               // B*N
    float* bval = ws + (size_t)BB * NN;              // B*64
    int* bidx = (int*)(bval + BB * 64);              // B*64
    float* wpart = bval + 2 * BB * 64;               // B*64*64
    float* sspart = wpart + (size_t)BB * 64 * 64;    // B*64

    k_init<<<dim3(BB * NN / 256), 256, 0, stream>>>(sc_in, score, sel_out);
    for (int it = 0; it < NBV; it++) {
        k_argmax1<<<dim3(64, BB), 256, 0, stream>>>(score, bval, bidx);
        k_iter<<<dim3(64, BB), 256, 0, stream>>>(x, score, bval, bidx, wpart, sspart, sim_out, it);
        k_fin<<<dim3(BB), 64, 0, stream>>>(wpart, sspart, vec_out, it);
    }
}

// Round 4
// 547.601 us; speedup vs baseline: 1.1523x; 1.1523x over previous
//
#include <hip/hip_runtime.h>

#define BB 16
#define CC 64
#define NN 65536
#define NBV 4
#define B64 (BB * 64)

// ws layout (fp32 elems): score B*N | bval 2*B64 | bidx 2*B64 (int) | wpart B*64*64 | sspart B*64

// Initial argmax over score_init (64 blocks/batch x 1024 scores) + zero selectedPos.
// Tie rule everywhere: larger value wins; equal -> smaller index (np.argmax = first max).
__global__ __launch_bounds__(256)
void k_argmax1(const float* __restrict__ sc_in,
               float* __restrict__ bval, int* __restrict__ bidx,
               float* __restrict__ sel_out) {
    int b = blockIdx.y, blk = blockIdx.x, tid = threadIdx.x;
    const float* s = sc_in + (size_t)b * NN + blk * 1024;
    float v = -1e30f; int vi = 0x7fffffff;
    #pragma unroll
    for (int k = 0; k < 4; k++) {
        int idx = k * 256 + tid;               // ascending per thread; strict > keeps earliest
        float xv = s[idx];
        if (xv > v) { v = xv; vi = blk * 1024 + idx; }
    }
    size_t gt = ((size_t)(b * 64 + blk)) * 256 + tid;   // 262144 threads x 4 = B*N
    #pragma unroll
    for (int k = 0; k < 4; k++) sel_out[gt + (size_t)k * 262144] = 0.f;
    __shared__ float sv[256]; __shared__ int si[256];
    sv[tid] = v; si[tid] = vi;
    __syncthreads();
    for (int st = 128; st > 0; st >>= 1) {
        if (tid < st) {
            float ov = sv[tid + st]; int oi = si[tid + st];
            if (ov > sv[tid] || (ov == sv[tid] && oi < si[tid])) { sv[tid] = ov; si[tid] = oi; }
        }
        __syncthreads();
    }
    if (tid == 0) { bval[b * 64 + blk] = sv[0]; bidx[b * 64 + blk] = si[0]; }
}

// Main per-iteration kernel. grid=(64,B), 256 thr = 4 waves; wave w owns channels 16w..16w+15.
// Per 64-pixel group: each thread loads 16 ch for its lane-pixel, partial d2 -> LDS (dbuf),
// one barrier, full d2 -> sim, 16 acc FMAs. Wave 0 also: sim_out store, score RMW (prefetch d1),
// running block-argmax of the NEW score (fused stage-1 for the next iteration; ping-pong bval).
__global__ __launch_bounds__(256, 4)
void k_iter(const float* __restrict__ x, const float* __restrict__ score_in,
            float* __restrict__ score_out,
            float* __restrict__ bval, int* __restrict__ bidx,
            float* __restrict__ wpart, float* __restrict__ sspart,
            float* __restrict__ sim_out, int iter) {
    int b = blockIdx.y, blk = blockIdx.x, tid = threadIdx.x;
    int lane = tid & 63, wv = tid >> 6;
    __shared__ float raw_s[64];
    __shared__ float d2p[2][4][64];

    int rb = (iter & 1) * B64, wb = ((iter & 1) ^ 1) * B64;

    if (tid < 64) {   // finish argmax over 64 block partials, fetch selected pixel's features
        float v = bval[rb + b * 64 + tid]; int vi = bidx[rb + b * 64 + tid];
        #pragma unroll
        for (int off = 32; off >= 1; off >>= 1) {
            float ov = __shfl_down(v, off, 64); int oi = __shfl_down(vi, off, 64);
            if (ov > v || (ov == v && oi < vi)) { v = ov; vi = oi; }
        }
        int ind = __shfl(vi, 0, 64);
        raw_s[tid] = x[((size_t)b * 64 + tid) * NN + ind];
    }
    __syncthreads();

    const float* xb = x + ((size_t)b * 64 + wv * 16) * NN;
    float raw[16];
    #pragma unroll
    for (int j = 0; j < 16; j++) raw[j] = raw_s[wv * 16 + j];
    float acc[16];
    #pragma unroll
    for (int j = 0; j < 16; j++) acc[j] = 0.f;

    const size_t sb = (size_t)b * NN;
    const size_t simb = (size_t)(b * NBV + iter) * NN;
    const int nbase = blk * 1024 + lane;
    const bool w0 = (wv == 0), upd = (iter < 3);

    float ssacc = 0.f, smax = -1e30f; int smaxi = 0;
    float sc_next = (w0 && upd) ? score_in[sb + nbase] : 0.f;   // depth-1 prefetch

    #pragma unroll 1
    for (int g = 0; g < 16; g++) {
        int n = nbase + g * 64;
        float xv[16], d2 = 0.f;
        #pragma unroll
        for (int j = 0; j < 16; j++) xv[j] = xb[(size_t)j * NN + n];
        float sc_cur = sc_next;
        if (w0 && upd && g < 15) sc_next = score_in[sb + n + 64];
        #pragma unroll
        for (int j = 0; j < 16; j++) { float df = xv[j] - raw[j]; d2 = fmaf(df, df, d2); }
        d2p[g & 1][wv][lane] = d2;
        __syncthreads();
        float d2s = (d2p[g & 1][0][lane] + d2p[g & 1][1][lane]) +
                    (d2p[g & 1][2][lane] + d2p[g & 1][3][lane]);
        float sim = expf(-sqrtf(fmaxf(d2s, 1e-12f)) * 0.05f);
        #pragma unroll
        for (int j = 0; j < 16; j++) acc[j] = fmaf(sim, xv[j], acc[j]);
        if (w0) {
            ssacc += sim;
            sim_out[simb + n] = sim;
            if (upd) {
                float sc = sc_cur * (1.f - sim);
                score_out[sb + n] = sc;
                if (sc > smax) { smax = sc; smaxi = n; }   // ascending n: strict > = first max
            }
        }
    }

    // per-channel cross-lane reduce; lane 0 writes block partial
    #pragma unroll
    for (int j = 0; j < 16; j++) {
        float v = acc[j];
        #pragma unroll
        for (int off = 32; off >= 1; off >>= 1) v += __shfl_down(v, off, 64);
        if (lane == 0) wpart[(((size_t)b * 64) + blk) * 64 + wv * 16 + j] = v;
    }
    if (w0) {
        float v = ssacc;
        #pragma unroll
        for (int off = 32; off >= 1; off >>= 1) v += __shfl_down(v, off, 64);
        if (lane == 0) sspart[b * 64 + blk] = v;
        if (upd) {
            #pragma unroll
            for (int off = 32; off >= 1; off >>= 1) {
                float ov = __shfl_down(smax, off, 64); int oi = __shfl_down(smaxi, off, 64);
                if (ov > smax || (ov == smax && oi < smaxi)) { smax = ov; smaxi = oi; }
            }
            if (lane == 0) { bval[wb + b * 64 + blk] = smax; bidx[wb + b * 64 + blk] = smaxi; }
        }
    }
}

__global__ void k_fin(const float* __restrict__ wpart, const float* __restrict__ sspart,
                      float* __restrict__ vec_out, int iter) {
    int b = blockIdx.x, tid = threadIdx.x;  // 64 threads
    float w = 0.f;
    for (int blk = 0; blk < 64; blk++) w += wpart[(((size_t)b * 64) + blk) * 64 + tid];
    float ss = 0.f;
    for (int blk = 0; blk < 64; blk++) ss += sspart[b * 64 + blk];
    vec_out[(b * NBV + iter) * 64 + tid] = w / ss;
}

extern "C" void kernel_launch(void* const* d_in, const int* in_sizes, int n_in,
                              void* d_out, int out_size, void* d_ws, size_t ws_size,
                              hipStream_t stream) {
    const float* x = (const float*)d_in[0];          // [B,C,H,W] fp32
    const float* sc_in = (const float*)d_in[1];      // [B,N] fp32
    float* out = (float*)d_out;                      // fp32 outputs
    float* vec_out = out;                            // B*4*C
    float* sim_out = vec_out + (size_t)BB * NBV * CC;// B*4*N
    float* sel_out = sim_out + (size_t)BB * NBV * NN;// B*N

    float* ws = (float*)d_ws;
    float* score = ws;                               // B*N
    float* bval = ws + (size_t)BB * NN;              // 2*B64
    int* bidx = (int*)(bval + 2 * B64);              // 2*B64
    float* wpart = bval + 4 * B64;                   // B*64*64
    float* sspart = wpart + (size_t)BB * 64 * 64;    // B*64

    k_argmax1<<<dim3(64, BB), 256, 0, stream>>>(sc_in, bval, bidx, sel_out);
    for (int it = 0; it < NBV; it++) {
        const float* s_in = (it == 0) ? sc_in : score;
        k_iter<<<dim3(64, BB), 256, 0, stream>>>(x, s_in, score, bval, bidx,
                                                 wpart, sspart, sim_out, it);
        k_fin<<<dim3(BB), 64, 0, stream>>>(wpart, sspart, vec_out, it);
    }
}

// Round 5
// 546.107 us; speedup vs baseline: 1.1554x; 1.0027x over previous
//
#include <hip/hip_runtime.h>

#define BB 16
#define CC 64
#define NN 65536
#define NBV 4
#define B64 (BB * 64)

// ws layout (fp32 elems): score B*N | bval 2*B64 | bidx 2*B64 (int) | wpart B*64*64 | sspart B*64

// Initial argmax over score_init (64 blocks/batch x 1024 scores) + zero selectedPos.
// Tie rule everywhere: larger value wins; equal -> smaller index (np.argmax = first max).
__global__ __launch_bounds__(256)
void k_argmax1(const float* __restrict__ sc_in,
               float* __restrict__ bval, int* __restrict__ bidx,
               float* __restrict__ sel_out) {
    int b = blockIdx.y, blk = blockIdx.x, tid = threadIdx.x;
    const float* s = sc_in + (size_t)b * NN + blk * 1024;
    float v = -1e30f; int vi = 0x7fffffff;
    #pragma unroll
    for (int k = 0; k < 4; k++) {
        int idx = k * 256 + tid;               // ascending per thread; strict > keeps earliest
        float xv = s[idx];
        if (xv > v) { v = xv; vi = blk * 1024 + idx; }
    }
    size_t gt = ((size_t)(b * 64 + blk)) * 256 + tid;   // 262144 threads x 4 = B*N
    #pragma unroll
    for (int k = 0; k < 4; k++) sel_out[gt + (size_t)k * 262144] = 0.f;
    __shared__ float sv[256]; __shared__ int si[256];
    sv[tid] = v; si[tid] = vi;
    __syncthreads();
    for (int st = 128; st > 0; st >>= 1) {
        if (tid < st) {
            float ov = sv[tid + st]; int oi = si[tid + st];
            if (ov > sv[tid] || (ov == sv[tid] && oi < si[tid])) { sv[tid] = ov; si[tid] = oi; }
        }
        __syncthreads();
    }
    if (tid == 0) { bval[b * 64 + blk] = sv[0]; bidx[b * 64 + blk] = si[0]; }
}

// Main per-iteration kernel. grid=(64,B), 256 thr = 4 waves; wave w owns channels 16w..16w+15.
// float4 everywhere: lane owns 4 pixels/group, 4 groups of 256 px per block.
// Per group: 16x global_load_dwordx4 (1 KB/wave/instr), partial d2 (float4) -> LDS dbuf,
// one barrier, cross-wave d2 sum -> sim4, 64 acc FMAs. Wave 0: sim/score float4 I/O +
// fused stage-1 argmax of the NEW score for the next iteration (ping-pong bval/bidx).
__global__ __launch_bounds__(256, 2)
void k_iter(const float* __restrict__ x, const float* __restrict__ score_in,
            float* __restrict__ score_out,
            float* __restrict__ bval, int* __restrict__ bidx,
            float* __restrict__ wpart, float* __restrict__ sspart,
            float* __restrict__ sim_out, int iter) {
    int b = blockIdx.y, blk = blockIdx.x, tid = threadIdx.x;
    int lane = tid & 63, wv = tid >> 6;
    __shared__ float raw_s[64];
    __shared__ float4 d2p[2][4][64];

    int rb = (iter & 1) * B64, wb = ((iter & 1) ^ 1) * B64;

    if (tid < 64) {   // finish argmax over 64 block partials, fetch selected pixel's features
        float v = bval[rb + b * 64 + tid]; int vi = bidx[rb + b * 64 + tid];
        #pragma unroll
        for (int off = 32; off >= 1; off >>= 1) {
            float ov = __shfl_down(v, off, 64); int oi = __shfl_down(vi, off, 64);
            if (ov > v || (ov == v && oi < vi)) { v = ov; vi = oi; }
        }
        int ind = __shfl(vi, 0, 64);
        raw_s[tid] = x[((size_t)b * 64 + tid) * NN + ind];
    }
    __syncthreads();

    const float* xb = x + ((size_t)b * 64 + wv * 16) * NN;
    float raw[16];
    #pragma unroll
    for (int j = 0; j < 16; j++) raw[j] = raw_s[wv * 16 + j];
    float acc[16];
    #pragma unroll
    for (int j = 0; j < 16; j++) acc[j] = 0.f;

    const size_t sb = (size_t)b * NN;
    const size_t simb = (size_t)(b * NBV + iter) * NN;
    const bool w0 = (wv == 0), upd = (iter < 3);

    float ssacc = 0.f, smax = -1e30f; int smaxi = 0;
    float4 sc_next;
    if (w0 && upd) sc_next = *(const float4*)(score_in + sb + blk * 1024 + lane * 4);

    #pragma unroll 1
    for (int g = 0; g < 4; g++) {
        int n0 = blk * 1024 + g * 256 + lane * 4;
        float4 xv[16];
        #pragma unroll
        for (int j = 0; j < 16; j++) xv[j] = *(const float4*)(xb + (size_t)j * NN + n0);
        float4 sc_cur = sc_next;
        if (w0 && upd && g < 3) sc_next = *(const float4*)(score_in + sb + n0 + 256);
        float4 d2 = make_float4(0.f, 0.f, 0.f, 0.f);
        #pragma unroll
        for (int j = 0; j < 16; j++) {
            float r = raw[j];
            float dx = xv[j].x - r, dy = xv[j].y - r, dz = xv[j].z - r, dw = xv[j].w - r;
            d2.x = fmaf(dx, dx, d2.x); d2.y = fmaf(dy, dy, d2.y);
            d2.z = fmaf(dz, dz, d2.z); d2.w = fmaf(dw, dw, d2.w);
        }
        d2p[g & 1][wv][lane] = d2;
        __syncthreads();
        float4 a0 = d2p[g & 1][0][lane], a1 = d2p[g & 1][1][lane];
        float4 a2 = d2p[g & 1][2][lane], a3 = d2p[g & 1][3][lane];
        float4 sim;
        sim.x = expf(-sqrtf(fmaxf((a0.x + a1.x) + (a2.x + a3.x), 1e-12f)) * 0.05f);
        sim.y = expf(-sqrtf(fmaxf((a0.y + a1.y) + (a2.y + a3.y), 1e-12f)) * 0.05f);
        sim.z = expf(-sqrtf(fmaxf((a0.z + a1.z) + (a2.z + a3.z), 1e-12f)) * 0.05f);
        sim.w = expf(-sqrtf(fmaxf((a0.w + a1.w) + (a2.w + a3.w), 1e-12f)) * 0.05f);
        #pragma unroll
        for (int j = 0; j < 16; j++) {
            acc[j] = fmaf(sim.x, xv[j].x, acc[j]);
            acc[j] = fmaf(sim.y, xv[j].y, acc[j]);
            acc[j] = fmaf(sim.z, xv[j].z, acc[j]);
            acc[j] = fmaf(sim.w, xv[j].w, acc[j]);
        }
        if (w0) {
            ssacc += (sim.x + sim.y) + (sim.z + sim.w);
            *(float4*)(sim_out + simb + n0) = sim;
            if (upd) {
                float4 sc;
                sc.x = sc_cur.x * (1.f - sim.x);
                sc.y = sc_cur.y * (1.f - sim.y);
                sc.z = sc_cur.z * (1.f - sim.z);
                sc.w = sc_cur.w * (1.f - sim.w);
                *(float4*)(score_out + sb + n0) = sc;
                // ascending n within lane; strict > = first max
                if (sc.x > smax) { smax = sc.x; smaxi = n0; }
                if (sc.y > smax) { smax = sc.y; smaxi = n0 + 1; }
                if (sc.z > smax) { smax = sc.z; smaxi = n0 + 2; }
                if (sc.w > smax) { smax = sc.w; smaxi = n0 + 3; }
            }
        }
    }

    // per-channel cross-lane reduce; lane 0 writes block partial
    #pragma unroll
    for (int j = 0; j < 16; j++) {
        float v = acc[j];
        #pragma unroll
        for (int off = 32; off >= 1; off >>= 1) v += __shfl_down(v, off, 64);
        if (lane == 0) wpart[(((size_t)b * 64) + blk) * 64 + wv * 16 + j] = v;
    }
    if (w0) {
        float v = ssacc;
        #pragma unroll
        for (int off = 32; off >= 1; off >>= 1) v += __shfl_down(v, off, 64);
        if (lane == 0) sspart[b * 64 + blk] = v;
        if (upd) {
            #pragma unroll
            for (int off = 32; off >= 1; off >>= 1) {
                float ov = __shfl_down(smax, off, 64); int oi = __shfl_down(smaxi, off, 64);
                if (ov > smax || (ov == smax && oi < smaxi)) { smax = ov; smaxi = oi; }
            }
            if (lane == 0) { bval[wb + b * 64 + blk] = smax; bidx[wb + b * 64 + blk] = smaxi; }
        }
    }
}

__global__ void k_fin(const float* __restrict__ wpart, const float* __restrict__ sspart,
                      float* __restrict__ vec_out, int iter) {
    int b = blockIdx.x, tid = threadIdx.x;  // 64 threads
    float w = 0.f;
    for (int blk = 0; blk < 64; blk++) w += wpart[(((size_t)b * 64) + blk) * 64 + tid];
    float ss = 0.f;
    for (int blk = 0; blk < 64; blk++) ss += sspart[b * 64 + blk];
    vec_out[(b * NBV + iter) * 64 + tid] = w / ss;
}

extern "C" void kernel_launch(void* const* d_in, const int* in_sizes, int n_in,
                              void* d_out, int out_size, void* d_ws, size_t ws_size,
                              hipStream_t stream) {
    const float* x = (const float*)d_in[0];          // [B,C,H,W] fp32
    const float* sc_in = (const float*)d_in[1];      // [B,N] fp32
    float* out = (float*)d_out;                      // fp32 outputs
    float* vec_out = out;                            // B*4*C
    float* sim_out = vec_out + (size_t)BB * NBV * CC;// B*4*N
    float* sel_out = sim_out + (size_t)BB * NBV * NN;// B*N

    float* ws = (float*)d_ws;
    float* score = ws;                               // B*N
    float* bval = ws + (size_t)BB * NN;              // 2*B64
    int* bidx = (int*)(bval + 2 * B64);              // 2*B64
    float* wpart = bval + 4 * B64;                   // B*64*64
    float* sspart = wpart + (size_t)BB * 64 * 64;    // B*64

    k_argmax1<<<dim3(64, BB), 256, 0, stream>>>(sc_in, bval, bidx, sel_out);
    for (int it = 0; it < NBV; it++) {
        const float* s_in = (it == 0) ? sc_in : score;
        k_iter<<<dim3(64, BB), 256, 0, stream>>>(x, s_in, score, bval, bidx,
                                                 wpart, sspart, sim_out, it);
        k_fin<<<dim3(BB), 64, 0, stream>>>(wpart, sspart, vec_out, it);
    }
}